// Round 6
// baseline (398.136 us; speedup 1.0000x reference)
//
#include <hip/hip_runtime.h>
#include <hip/hip_bf16.h>

typedef __attribute__((ext_vector_type(4))) float f32x4;
typedef __attribute__((ext_vector_type(2))) float f32x2;
typedef __attribute__((ext_vector_type(8))) short s16x8;
typedef __attribute__((ext_vector_type(4))) short s16x4;

constexpr int T_SEQ = 2048;
constexpr int D = 64;        // head channels
constexpr int H = 16;        // heads
constexpr int QBLK = 128;    // q rows per block (16 per wave, 8 waves)
constexpr int KVBLK = 64;    // kv rows per iteration
constexpr int NT = T_SEQ / KVBLK;  // 32 tiles
constexpr int NTHREADS = 512;
constexpr float LOG2E = 1.44269504088896340736f;

// native f32->bf16 (RNE): compiler emits v_cvt_pk_bf16_f32 for pairs (m240)
__device__ __forceinline__ short f2bf(float f) {
  return (short)__builtin_bit_cast(unsigned short, __float2bfloat16(f));
}

__device__ __forceinline__ float fast_exp2(float x) {
#if __has_builtin(__builtin_amdgcn_exp2f)
  return __builtin_amdgcn_exp2f(x);
#else
  return exp2f(x);
#endif
}

// XOR swizzle for [rows][64] bf16 tiles (128B rows). Bijective per 8-row
// stripe; touches byte bits 4..6 only -> preserves 8B/16B alignment.
__device__ __forceinline__ int swz(int row, int colByte) {
  return row * 128 + (colByte ^ ((row & 7) << 4));
}

__global__ __launch_bounds__(NTHREADS, 6)
void attn_kernel(const float* __restrict__ qkv, const float* __restrict__ mask,
                 float* __restrict__ out) {
  __shared__ __align__(16) char smem[40960];
  // phase 1: Qstage [128 q][64 c] bf16 swz @0 (16 KB, dies after frag extract)
  // steady:  Kc [64 s][64 c] @0 (8K); Vc [64 c][64 s] @8K; Pc 8x2KB @16K;
  //          maskLds f32[2048] @32768 (8K)
  char* Qc = smem;
  char* Kc = smem;
  char* Vc = smem + 8192;
  char* Pc = smem + 16384;
  float* maskLds = (float*)(smem + 32768);

  const int tid = threadIdx.x;
  // T1: XCD-aware swizzle — all 16 q-tiles of one bh land on one XCD's L2.
  int flat = blockIdx.y * 16 + blockIdx.x;       // 0..1023, dispatch xcd=flat&7
  flat = (flat & 7) * 128 + (flat >> 3);          // bijection (1024 = 8*128)
  const int qt = flat & 15;
  const int bh = flat >> 4;
  const int b = bh >> 4, h = bh & 15;

  const size_t headBase = ((size_t)b * (3 * H * D) + (size_t)h * (3 * D)) * T_SEQ;
  const float* gQ = qkv + headBase;
  const float* gK = gQ + (size_t)D * T_SEQ;
  const float* gV = gQ + (size_t)(2 * D) * T_SEQ;
  // reference quirk: jnp.tile(mask,(H,1)) -> row (b*H+h) % N == h % 4
  const float* gM = mask + (size_t)(bh & 3) * T_SEQ;

  // ---- per-thread staging geometry (K waves 0-3, V waves 4-7) ----
  const bool isK = tid < 256;
  const int t2 = tid & 255;
  const int ksb = 2 * (t2 & 31);        // K: s offset (2 rows)
  const int kcb = 8 * (t2 >> 5);        // K: 8 channels
  const int vc = t2 >> 2;               // V: channel
  const int vsb = 16 * (t2 & 3);        // V: 16 s
  // unified issue: 8x f32x2 loads at stagBase + s + j*sstride
  const float* stagBase = isK ? (gK + (size_t)kcb * T_SEQ + ksb)
                              : (gV + (size_t)vc * T_SEQ + vsb);
  const int sstride = isK ? T_SEQ : 2;
  f32x2 stg[8];   // in-flight K/V raw data (issued tile t+1, consumed t+1)

  // ---- prologue: mask row (8KB) + stage Q transposed [q][c] ----
  *(f32x4*)&maskLds[tid * 4] = *(const f32x4*)&gM[tid * 4];
  {
    const int sb = (tid & 31) * 4;   // q within tile
    const int cb = (tid >> 5) * 4;   // channel
    const int q0 = qt * QBLK;
    const float qscale = 0.125f * LOG2E;  // 1/sqrt(64) * log2(e) folded in
    f32x4 r[4];
#pragma unroll
    for (int j = 0; j < 4; ++j)
      r[j] = *(const f32x4*)(gQ + (size_t)(cb + j) * T_SEQ + q0 + sb);
#pragma unroll
    for (int i = 0; i < 4; ++i) {
      s16x4 w;
#pragma unroll
      for (int j = 0; j < 4; ++j) w[j] = f2bf(r[j][i] * qscale);
      *(s16x4*)(Qc + swz(sb + i, 2 * cb)) = w;
    }
  }
  __syncthreads();

  const int wave = tid >> 6, lane = tid & 63;
  const int lg = lane >> 4, lid = lane & 15;

  // Q B-fragments for swapped QK^T: lane holds Q[q=wave*16+lid][k-slot 8lg+e]
  s16x8 aq[2];
#pragma unroll
  for (int ko = 0; ko < 2; ++ko)
    aq[ko] = *(const s16x8*)(Qc + swz(wave * 16 + lid, 16 * lg + 64 * ko));

  // issue tile-0 K/V loads (drained by the next barrier — one-time cost)
#pragma unroll
  for (int j = 0; j < 8; ++j)
    stg[j] = *(const f32x2*)(stagBase + j * sstride);

  // per-lane softmax state (log2 domain) for q = qt*128 + wave*16 + lid
  float m0 = -1e30f, l0 = 0.0f;
  f32x4 accO[4];   // accO[ct][r] = O^T[c=16ct+4lg+r][q=lid]
#pragma unroll
  for (int ct = 0; ct < 4; ++ct) accO[ct] = (f32x4){0.f, 0.f, 0.f, 0.f};

  char* Pw = Pc + wave * 2048;     // [16 q=lid][64 s] bf16 swz

  __syncthreads();  // aq reads done (Qc dead) + tile-0 loads arrived

  for (int s0 = 0; s0 < T_SEQ; s0 += KVBLK) {
    // ---- convert stg -> LDS tile (data arrived during previous compute) ----
    if (isK) {
      // K transposed [s][c]: 2s x 8c, b128 writes
#pragma unroll
      for (int i = 0; i < 2; ++i) {
        s16x8 w;
#pragma unroll
        for (int j = 0; j < 8; ++j) w[j] = f2bf(stg[j][i]);
        *(s16x8*)(Kc + swz(ksb + i, 2 * kcb)) = w;
      }
    } else {
      // V natural [c][s], mask folded in (P*mask@V == P@(V.*mask))
      f32x4 mk[4];
#pragma unroll
      for (int i = 0; i < 4; ++i)
        mk[i] = *(const f32x4*)&maskLds[s0 + vsb + 4 * i];
      s16x8 w0, w1;
#pragma unroll
      for (int j = 0; j < 8; ++j)
        w0[j] = f2bf(stg[j >> 1][j & 1] * mk[j >> 2][j & 3]);
#pragma unroll
      for (int j = 0; j < 8; ++j)
        w1[j] = f2bf(stg[4 + (j >> 1)][j & 1] * mk[2 + (j >> 2)][j & 3]);
      *(s16x8*)(Vc + swz(vc, 2 * vsb)) = w0;
      *(s16x8*)(Vc + swz(vc, 2 * vsb + 16)) = w1;
    }
    __syncthreads();   // LDS tile visible to all waves

    // ---- issue next tile's loads: in flight across the whole compute ----
    if (s0 + KVBLK < T_SEQ) {
      const float* src = stagBase + (s0 + KVBLK);
#pragma unroll
      for (int j = 0; j < 8; ++j)
        stg[j] = *(const f32x2*)(src + j * sstride);
    }

    // ---- S^T = mfma(K, Q): C[s=16nt+4lg+r][q=lid], log2-scaled ----
    f32x4 accST[4];
#pragma unroll
    for (int nt = 0; nt < 4; ++nt) accST[nt] = (f32x4){0.f, 0.f, 0.f, 0.f};
    __builtin_amdgcn_s_setprio(1);
#pragma unroll
    for (int ko = 0; ko < 2; ++ko) {
#pragma unroll
      for (int nt = 0; nt < 4; ++nt) {
        s16x8 ak = *(const s16x8*)(Kc + swz(nt * 16 + lid, 16 * lg + 64 * ko));
        accST[nt] = __builtin_amdgcn_mfma_f32_16x16x32_bf16(ak, aq[ko], accST[nt], 0, 0, 0);
      }
    }
    __builtin_amdgcn_s_setprio(0);

    // ---- per-lane online softmax (lane owns q=lid; s spread over lg) ----
    float mx[4];
#pragma unroll
    for (int nt = 0; nt < 4; ++nt)
      mx[nt] = fmaxf(fmaxf(accST[nt][0], accST[nt][1]),
                     fmaxf(accST[nt][2], accST[nt][3]));
    float tm = fmaxf(fmaxf(mx[0], mx[1]), fmaxf(mx[2], mx[3]));
    tm = fmaxf(tm, __shfl_xor(tm, 16));
    tm = fmaxf(tm, __shfl_xor(tm, 32));
    // T13 defer-rescale (log2 domain: 8*log2e)
    if (!__all(tm - m0 <= 11.5416f)) {
      const float nm = fmaxf(m0, tm);
      const float sc = fast_exp2(m0 - nm);
      m0 = nm;
      l0 *= sc;
#pragma unroll
      for (int ct = 0; ct < 4; ++ct) {
#pragma unroll
        for (int r = 0; r < 4; ++r) accO[ct][r] *= sc;
      }
    }
    float p[4][4], ps[4];
#pragma unroll
    for (int nt = 0; nt < 4; ++nt) {
#pragma unroll
      for (int r = 0; r < 4; ++r) p[nt][r] = fast_exp2(accST[nt][r] - m0);
      ps[nt] = (p[nt][0] + p[nt][1]) + (p[nt][2] + p[nt][3]);
    }
    float rs = (ps[0] + ps[1]) + (ps[2] + ps[3]);
    rs += __shfl_xor(rs, 16);
    rs += __shfl_xor(rs, 32);
    l0 += rs;   // denominator unmasked (ref: softmax before mask)

    // ---- P -> per-wave LDS, 4x 8B writes (conflict-free, pk-converts) ----
#pragma unroll
    for (int nt = 0; nt < 4; ++nt) {
      s16x4 w;
#pragma unroll
      for (int r = 0; r < 4; ++r) w[r] = f2bf(p[nt][r]);
      *(s16x4*)(Pw + swz(lid, 32 * nt + 8 * lg)) = w;
    }

    // ---- O^T += mfma(V, P): C[c=16ct+4lg+r][q=lid] ----
    // per-wave DS in-order: no barrier needed for Pw write->read
    __builtin_amdgcn_s_setprio(1);
#pragma unroll
    for (int ko = 0; ko < 2; ++ko) {
      s16x8 bp = *(const s16x8*)(Pw + swz(lid, 64 * ko + 16 * lg));
#pragma unroll
      for (int ct = 0; ct < 4; ++ct) {
        s16x8 av = *(const s16x8*)(Vc + swz(ct * 16 + lid, 64 * ko + 16 * lg));
        accO[ct] = __builtin_amdgcn_mfma_f32_16x16x32_bf16(av, bp, accO[ct], 0, 0, 0);
      }
    }
    __builtin_amdgcn_s_setprio(0);

    // bottom barrier: all reads of tile done; its vmcnt(0) drain waits for
    // the NEXT tile's loads — which had the whole compute phase to land.
    __syncthreads();
  }

  // ---- epilogue: direct stores, lanes lid=0..15 give 64B segments ----
  const float rcp = 1.0f / l0;
  const int qcol = qt * QBLK + wave * 16 + lid;
#pragma unroll
  for (int ct = 0; ct < 4; ++ct) {
#pragma unroll
    for (int r = 0; r < 4; ++r) {
      const int c = 16 * ct + 4 * lg + r;
      out[((size_t)(b * (H * D) + h * D + c)) * T_SEQ + qcol] = accO[ct][r] * rcp;
    }
  }
}

extern "C" void kernel_launch(void* const* d_in, const int* in_sizes, int n_in,
                              void* d_out, int out_size, void* d_ws, size_t ws_size,
                              hipStream_t stream) {
  const float* qkv = (const float*)d_in[0];
  const float* mask = (const float*)d_in[1];
  float* out = (float*)d_out;
  dim3 grid(T_SEQ / QBLK, 64);  // 16 q-tiles x 64 batch-heads
  attn_kernel<<<grid, NTHREADS, 0, stream>>>(qkv, mask, out);
}

// Round 7
// 395.694 us; speedup vs baseline: 1.0062x; 1.0062x over previous
//
#include <hip/hip_runtime.h>
#include <hip/hip_bf16.h>

typedef __attribute__((ext_vector_type(4))) float f32x4;
typedef __attribute__((ext_vector_type(2))) float f32x2;
typedef __attribute__((ext_vector_type(8))) short s16x8;
typedef __attribute__((ext_vector_type(4))) short s16x4;

constexpr int T_SEQ = 2048;
constexpr int D = 64;        // head channels
constexpr int H = 16;        // heads
constexpr int QBLK = 128;    // q rows per block (16 per wave, 8 waves)
constexpr int KVBLK = 64;    // kv rows per iteration
constexpr int NTHREADS = 512;
constexpr float LOG2E = 1.44269504088896340736f;

// native f32->bf16 (RNE): compiler emits v_cvt_pk_bf16_f32 for pairs (m240)
__device__ __forceinline__ short f2bf(float f) {
  return (short)__builtin_bit_cast(unsigned short, __float2bfloat16(f));
}

__device__ __forceinline__ float fast_exp2(float x) {
#if __has_builtin(__builtin_amdgcn_exp2f)
  return __builtin_amdgcn_exp2f(x);
#else
  return exp2f(x);
#endif
}

// XOR swizzle for [rows][64] bf16 tiles (128B rows). Bijective per 8-row
// stripe; touches byte bits 4..6 only -> preserves 8B/16B alignment.
__device__ __forceinline__ int swz(int row, int colByte) {
  return row * 128 + (colByte ^ ((row & 7) << 4));
}

__global__ __launch_bounds__(NTHREADS, 6)
void attn_kernel(const float* __restrict__ qkv, const float* __restrict__ mask,
                 float* __restrict__ out) {
  __shared__ __align__(16) char smem[40960];
  // phase 1: Qstage [128 q][64 c] bf16 swz @0 (16 KB, dies after frag extract)
  // steady:  Kc [64 s][64 c] @0 (8K); Vc [64 c][64 s] @8K; Pc 8x2KB @16K;
  //          maskLds f32[2048] @32768 (8K)
  char* Qc = smem;
  char* Kc = smem;
  char* Vc = smem + 8192;
  char* Pc = smem + 16384;
  float* maskLds = (float*)(smem + 32768);

  const int tid = threadIdx.x;
  // T1: XCD-aware swizzle — all 16 q-tiles of one bh land on one XCD's L2.
  int flat = blockIdx.y * 16 + blockIdx.x;       // 0..1023, dispatch xcd=flat&7
  flat = (flat & 7) * 128 + (flat >> 3);          // bijection (1024 = 8*128)
  const int qt = flat & 15;
  const int bh = flat >> 4;
  const int b = bh >> 4, h = bh & 15;

  const size_t headBase = ((size_t)b * (3 * H * D) + (size_t)h * (3 * D)) * T_SEQ;
  const float* gQ = qkv + headBase;
  const float* gK = gQ + (size_t)D * T_SEQ;
  const float* gV = gQ + (size_t)(2 * D) * T_SEQ;
  // reference quirk: jnp.tile(mask,(H,1)) -> row (b*H+h) % N == h % 4
  const float* gM = mask + (size_t)(bh & 3) * T_SEQ;

  // ---- per-thread staging geometry (K waves 0-3, V waves 4-7) ----
  const bool isK = tid < 256;
  const int t2 = tid & 255;
  const int ksb = 2 * (t2 & 31);        // K: s offset (2 rows)
  const int kcb = 8 * (t2 >> 5);        // K: 8 channels
  const int vc = t2 >> 2;               // V: channel
  const int vsb = 16 * (t2 & 3);        // V: 16 s
  // unified issue: 8x f32x2 loads at stagBase + s + j*sstride
  const float* stagBase = isK ? (gK + (size_t)kcb * T_SEQ + ksb)
                              : (gV + (size_t)vc * T_SEQ + vsb);
  const int sstride = isK ? T_SEQ : 2;
  // NAMED scalars (rule #20): guaranteed VGPR residency across barriers.
  f32x2 g0, g1, g2, g3, g4, g5, g6, g7;

  // ---- prologue: mask row (8KB) + stage Q transposed [q][c] ----
  *(f32x4*)&maskLds[tid * 4] = *(const f32x4*)&gM[tid * 4];
  {
    const int sb = (tid & 31) * 4;   // q within tile
    const int cb = (tid >> 5) * 4;   // channel
    const int q0 = qt * QBLK;
    const float qscale = 0.125f * LOG2E;  // 1/sqrt(64) * log2(e) folded in
    f32x4 r[4];
#pragma unroll
    for (int j = 0; j < 4; ++j)
      r[j] = *(const f32x4*)(gQ + (size_t)(cb + j) * T_SEQ + q0 + sb);
#pragma unroll
    for (int i = 0; i < 4; ++i) {
      s16x4 w;
#pragma unroll
      for (int j = 0; j < 4; ++j) w[j] = f2bf(r[j][i] * qscale);
      *(s16x4*)(Qc + swz(sb + i, 2 * cb)) = w;
    }
  }
  __syncthreads();

  const int wave = tid >> 6, lane = tid & 63;
  const int lg = lane >> 4, lid = lane & 15;

  // Q B-fragments for swapped QK^T: lane holds Q[q=wave*16+lid][k-slot 8lg+e]
  s16x8 aq[2];
#pragma unroll
  for (int ko = 0; ko < 2; ++ko)
    aq[ko] = *(const s16x8*)(Qc + swz(wave * 16 + lid, 16 * lg + 64 * ko));

  // issue tile-0 K/V loads (drained by the next barrier — one-time cost)
  g0 = *(const f32x2*)(stagBase + 0 * sstride);
  g1 = *(const f32x2*)(stagBase + 1 * sstride);
  g2 = *(const f32x2*)(stagBase + 2 * sstride);
  g3 = *(const f32x2*)(stagBase + 3 * sstride);
  g4 = *(const f32x2*)(stagBase + 4 * sstride);
  g5 = *(const f32x2*)(stagBase + 5 * sstride);
  g6 = *(const f32x2*)(stagBase + 6 * sstride);
  g7 = *(const f32x2*)(stagBase + 7 * sstride);

  // per-lane softmax state (log2 domain) for q = qt*128 + wave*16 + lid
  float m0 = -1e30f, l0 = 0.0f;
  f32x4 accO[4];   // accO[ct][r] = O^T[c=16ct+4lg+r][q=lid]
#pragma unroll
  for (int ct = 0; ct < 4; ++ct) accO[ct] = (f32x4){0.f, 0.f, 0.f, 0.f};

  char* Pw = Pc + wave * 2048;     // [16 q=lid][64 s] bf16 swz

  __syncthreads();  // aq reads done (Qc dead) + tile-0 loads arrived

  for (int s0 = 0; s0 < T_SEQ; s0 += KVBLK) {
    // ---- convert g0..g7 -> LDS tile (data landed during prior compute) ----
    if (isK) {
      // K transposed [s][c]: 2 rows x 8 channels, b128 writes
      s16x8 wA, wB;
      wA[0] = f2bf(g0[0]); wB[0] = f2bf(g0[1]);
      wA[1] = f2bf(g1[0]); wB[1] = f2bf(g1[1]);
      wA[2] = f2bf(g2[0]); wB[2] = f2bf(g2[1]);
      wA[3] = f2bf(g3[0]); wB[3] = f2bf(g3[1]);
      wA[4] = f2bf(g4[0]); wB[4] = f2bf(g4[1]);
      wA[5] = f2bf(g5[0]); wB[5] = f2bf(g5[1]);
      wA[6] = f2bf(g6[0]); wB[6] = f2bf(g6[1]);
      wA[7] = f2bf(g7[0]); wB[7] = f2bf(g7[1]);
      *(s16x8*)(Kc + swz(ksb + 0, 2 * kcb)) = wA;
      *(s16x8*)(Kc + swz(ksb + 1, 2 * kcb)) = wB;
    } else {
      // V natural [c][s], mask folded in (P*mask@V == P@(V.*mask))
      const f32x4 mk0 = *(const f32x4*)&maskLds[s0 + vsb + 0];
      const f32x4 mk1 = *(const f32x4*)&maskLds[s0 + vsb + 4];
      const f32x4 mk2 = *(const f32x4*)&maskLds[s0 + vsb + 8];
      const f32x4 mk3 = *(const f32x4*)&maskLds[s0 + vsb + 12];
      s16x8 w0, w1;
      w0[0] = f2bf(g0[0] * mk0[0]); w0[1] = f2bf(g0[1] * mk0[1]);
      w0[2] = f2bf(g1[0] * mk0[2]); w0[3] = f2bf(g1[1] * mk0[3]);
      w0[4] = f2bf(g2[0] * mk1[0]); w0[5] = f2bf(g2[1] * mk1[1]);
      w0[6] = f2bf(g3[0] * mk1[2]); w0[7] = f2bf(g3[1] * mk1[3]);
      w1[0] = f2bf(g4[0] * mk2[0]); w1[1] = f2bf(g4[1] * mk2[1]);
      w1[2] = f2bf(g5[0] * mk2[2]); w1[3] = f2bf(g5[1] * mk2[3]);
      w1[4] = f2bf(g6[0] * mk3[0]); w1[5] = f2bf(g6[1] * mk3[1]);
      w1[6] = f2bf(g7[0] * mk3[2]); w1[7] = f2bf(g7[1] * mk3[3]);
      *(s16x8*)(Vc + swz(vc, 2 * vsb)) = w0;
      *(s16x8*)(Vc + swz(vc, 2 * vsb + 16)) = w1;
    }
    __syncthreads();   // LDS tile visible to all waves

    // ---- issue next tile's loads; sched_barrier pins them above compute ----
    if (s0 + KVBLK < T_SEQ) {
      const float* src = stagBase + (s0 + KVBLK);
      g0 = *(const f32x2*)(src + 0 * sstride);
      g1 = *(const f32x2*)(src + 1 * sstride);
      g2 = *(const f32x2*)(src + 2 * sstride);
      g3 = *(const f32x2*)(src + 3 * sstride);
      g4 = *(const f32x2*)(src + 4 * sstride);
      g5 = *(const f32x2*)(src + 5 * sstride);
      g6 = *(const f32x2*)(src + 6 * sstride);
      g7 = *(const f32x2*)(src + 7 * sstride);
    }
    __builtin_amdgcn_sched_barrier(0);

    // ---- S^T = mfma(K, Q): C[s=16nt+4lg+r][q=lid], log2-scaled ----
    f32x4 accST[4];
#pragma unroll
    for (int nt = 0; nt < 4; ++nt) accST[nt] = (f32x4){0.f, 0.f, 0.f, 0.f};
    __builtin_amdgcn_s_setprio(1);
#pragma unroll
    for (int ko = 0; ko < 2; ++ko) {
#pragma unroll
      for (int nt = 0; nt < 4; ++nt) {
        s16x8 ak = *(const s16x8*)(Kc + swz(nt * 16 + lid, 16 * lg + 64 * ko));
        accST[nt] = __builtin_amdgcn_mfma_f32_16x16x32_bf16(ak, aq[ko], accST[nt], 0, 0, 0);
      }
    }
    __builtin_amdgcn_s_setprio(0);

    // ---- per-lane online softmax (lane owns q=lid; s spread over lg) ----
    float mx[4];
#pragma unroll
    for (int nt = 0; nt < 4; ++nt)
      mx[nt] = fmaxf(fmaxf(accST[nt][0], accST[nt][1]),
                     fmaxf(accST[nt][2], accST[nt][3]));
    float tm = fmaxf(fmaxf(mx[0], mx[1]), fmaxf(mx[2], mx[3]));
    tm = fmaxf(tm, __shfl_xor(tm, 16));
    tm = fmaxf(tm, __shfl_xor(tm, 32));
    // T13 defer-rescale (log2 domain: 8*log2e)
    if (!__all(tm - m0 <= 11.5416f)) {
      const float nm = fmaxf(m0, tm);
      const float sc = fast_exp2(m0 - nm);
      m0 = nm;
      l0 *= sc;
#pragma unroll
      for (int ct = 0; ct < 4; ++ct) {
#pragma unroll
        for (int r = 0; r < 4; ++r) accO[ct][r] *= sc;
      }
    }
    float p[4][4], ps[4];
#pragma unroll
    for (int nt = 0; nt < 4; ++nt) {
#pragma unroll
      for (int r = 0; r < 4; ++r) p[nt][r] = fast_exp2(accST[nt][r] - m0);
      ps[nt] = (p[nt][0] + p[nt][1]) + (p[nt][2] + p[nt][3]);
    }
    float rs = (ps[0] + ps[1]) + (ps[2] + ps[3]);
    rs += __shfl_xor(rs, 16);
    rs += __shfl_xor(rs, 32);
    l0 += rs;   // denominator unmasked (ref: softmax before mask)

    // ---- P -> per-wave LDS, 4x 8B writes (conflict-free, pk-converts) ----
#pragma unroll
    for (int nt = 0; nt < 4; ++nt) {
      s16x4 w;
#pragma unroll
      for (int r = 0; r < 4; ++r) w[r] = f2bf(p[nt][r]);
      *(s16x4*)(Pw + swz(lid, 32 * nt + 8 * lg)) = w;
    }

    // ---- O^T += mfma(V, P): C[c=16ct+4lg+r][q=lid] ----
    // per-wave DS in-order: no barrier needed for Pw write->read
    __builtin_amdgcn_s_setprio(1);
#pragma unroll
    for (int ko = 0; ko < 2; ++ko) {
      s16x8 bp = *(const s16x8*)(Pw + swz(lid, 64 * ko + 16 * lg));
#pragma unroll
      for (int ct = 0; ct < 4; ++ct) {
        s16x8 av = *(const s16x8*)(Vc + swz(ct * 16 + lid, 64 * ko + 16 * lg));
        accO[ct] = __builtin_amdgcn_mfma_f32_16x16x32_bf16(av, bp, accO[ct], 0, 0, 0);
      }
    }
    __builtin_amdgcn_s_setprio(0);

    // bottom barrier: all reads of tile done; its vmcnt(0) drain waits for
    // the NEXT tile's loads — which had the whole compute phase to land.
    __syncthreads();
  }

  // ---- epilogue: direct stores, lanes lid=0..15 give 64B segments ----
  const float rcp = 1.0f / l0;
  const int qcol = qt * QBLK + wave * 16 + lid;
#pragma unroll
  for (int ct = 0; ct < 4; ++ct) {
#pragma unroll
    for (int r = 0; r < 4; ++r) {
      const int c = 16 * ct + 4 * lg + r;
      out[((size_t)(b * (H * D) + h * D + c)) * T_SEQ + qcol] = accO[ct][r] * rcp;
    }
  }
}

extern "C" void kernel_launch(void* const* d_in, const int* in_sizes, int n_in,
                              void* d_out, int out_size, void* d_ws, size_t ws_size,
                              hipStream_t stream) {
  const float* qkv = (const float*)d_in[0];
  const float* mask = (const float*)d_in[1];
  float* out = (float*)d_out;
  dim3 grid(T_SEQ / QBLK, 64);  // 16 q-tiles x 64 batch-heads
  attn_kernel<<<grid, NTHREADS, 0, stream>>>(qkv, mask, out);
}

// Round 10
// 256.228 us; speedup vs baseline: 1.5538x; 1.5443x over previous
//
#include <hip/hip_runtime.h>
#include <hip/hip_bf16.h>

typedef __attribute__((ext_vector_type(4))) float f32x4;
typedef __attribute__((ext_vector_type(2))) float f32x2;
typedef __attribute__((ext_vector_type(8))) short s16x8;
typedef __attribute__((ext_vector_type(4))) short s16x4;

constexpr int T_SEQ = 2048;
constexpr int D = 64;        // head channels
constexpr int H = 16;        // heads
constexpr int QBLK = 128;    // q rows per block (16 per wave, 8 waves)
constexpr int KVBLK = 64;    // kv rows per iteration
constexpr int NTHREADS = 512;
constexpr float LOG2E = 1.44269504088896340736f;

// native f32->bf16 (RNE): compiler emits v_cvt_pk_bf16_f32 for pairs (m240)
__device__ __forceinline__ short f2bf(float f) {
  return (short)__builtin_bit_cast(unsigned short, __float2bfloat16(f));
}

__device__ __forceinline__ float fast_exp2(float x) {
#if __has_builtin(__builtin_amdgcn_exp2f)
  return __builtin_amdgcn_exp2f(x);
#else
  return exp2f(x);
#endif
}

// XOR swizzle for [rows][64] bf16 tiles (128B rows). Bijective per 8-row
// stripe; touches byte bits 4..6 only -> preserves 8B/16B alignment.
__device__ __forceinline__ int swz(int row, int colByte) {
  return row * 128 + (colByte ^ ((row & 7) << 4));
}

// Issue 8 f32x2 loads (tile at s-offset) into named regs g0..g7.
#define LOAD_G(SRC)                                \
  do {                                             \
    const float* _s = (SRC);                       \
    g0 = *(const f32x2*)(_s + 0 * sstride);        \
    g1 = *(const f32x2*)(_s + 1 * sstride);        \
    g2 = *(const f32x2*)(_s + 2 * sstride);        \
    g3 = *(const f32x2*)(_s + 3 * sstride);        \
    g4 = *(const f32x2*)(_s + 4 * sstride);        \
    g5 = *(const f32x2*)(_s + 5 * sstride);        \
    g6 = *(const f32x2*)(_s + 6 * sstride);        \
    g7 = *(const f32x2*)(_s + 7 * sstride);        \
  } while (0)

// Convert g0..g7 -> bf16 LDS tile (K transposed / V natural with mask fold).
#define CONVERT_STORE(KD, VD, SM)                                         \
  do {                                                                    \
    if (isK) {                                                            \
      s16x8 wA, wB;                                                       \
      wA[0] = f2bf(g0[0]); wB[0] = f2bf(g0[1]);                           \
      wA[1] = f2bf(g1[0]); wB[1] = f2bf(g1[1]);                           \
      wA[2] = f2bf(g2[0]); wB[2] = f2bf(g2[1]);                           \
      wA[3] = f2bf(g3[0]); wB[3] = f2bf(g3[1]);                           \
      wA[4] = f2bf(g4[0]); wB[4] = f2bf(g4[1]);                           \
      wA[5] = f2bf(g5[0]); wB[5] = f2bf(g5[1]);                           \
      wA[6] = f2bf(g6[0]); wB[6] = f2bf(g6[1]);                           \
      wA[7] = f2bf(g7[0]); wB[7] = f2bf(g7[1]);                           \
      *(s16x8*)((KD) + swz(ksb + 0, 2 * kcb)) = wA;                       \
      *(s16x8*)((KD) + swz(ksb + 1, 2 * kcb)) = wB;                       \
    } else {                                                              \
      const f32x4 mk0 = *(const f32x4*)&maskLds[(SM) + vsb + 0];          \
      const f32x4 mk1 = *(const f32x4*)&maskLds[(SM) + vsb + 4];          \
      const f32x4 mk2 = *(const f32x4*)&maskLds[(SM) + vsb + 8];          \
      const f32x4 mk3 = *(const f32x4*)&maskLds[(SM) + vsb + 12];         \
      s16x8 w0, w1;                                                       \
      w0[0] = f2bf(g0[0] * mk0[0]); w0[1] = f2bf(g0[1] * mk0[1]);         \
      w0[2] = f2bf(g1[0] * mk0[2]); w0[3] = f2bf(g1[1] * mk0[3]);         \
      w0[4] = f2bf(g2[0] * mk1[0]); w0[5] = f2bf(g2[1] * mk1[1]);         \
      w0[6] = f2bf(g3[0] * mk1[2]); w0[7] = f2bf(g3[1] * mk1[3]);         \
      w1[0] = f2bf(g4[0] * mk2[0]); w1[1] = f2bf(g4[1] * mk2[1]);         \
      w1[2] = f2bf(g5[0] * mk2[2]); w1[3] = f2bf(g5[1] * mk2[3]);         \
      w1[4] = f2bf(g6[0] * mk3[0]); w1[5] = f2bf(g6[1] * mk3[1]);         \
      w1[6] = f2bf(g7[0] * mk3[2]); w1[7] = f2bf(g7[1] * mk3[3]);         \
      *(s16x8*)((VD) + swz(vc, 2 * vsb)) = w0;                            \
      *(s16x8*)((VD) + swz(vc, 2 * vsb + 16)) = w1;                       \
    }                                                                     \
  } while (0)

__global__ __launch_bounds__(NTHREADS, 4)
void attn_kernel(const float* __restrict__ qkv, const float* __restrict__ mask,
                 float* __restrict__ out) {
  __shared__ __align__(16) char smem[57344];
  // K0 @0, K1 @8K, V0 @16K, V1 @24K, Pc @32K (16K), maskLds @48K (8K).
  // Qstage (16 KB) aliases Pc during the prologue only (NOT K0/K1 — keeps
  // g0..g7 from ever being live across a barrier).
  char* K0 = smem;
  char* K1 = smem + 8192;
  char* V0 = smem + 16384;
  char* V1 = smem + 24576;
  char* Pc = smem + 32768;
  float* maskLds = (float*)(smem + 49152);
  char* Qc = smem + 32768;   // aliases Pc (first Pw write is after a barrier
                             // whose lgkmcnt(0) drain orders all aq ds_reads)

  const int tid = threadIdx.x;
  // T1: XCD-aware swizzle — all 16 q-tiles of one bh land on one XCD's L2.
  int flat = blockIdx.y * 16 + blockIdx.x;       // 0..1023, dispatch xcd=flat&7
  flat = (flat & 7) * 128 + (flat >> 3);          // bijection (1024 = 8*128)
  const int qt = flat & 15;
  const int bh = flat >> 4;
  const int b = bh >> 4, h = bh & 15;

  const size_t headBase = ((size_t)b * (3 * H * D) + (size_t)h * (3 * D)) * T_SEQ;
  const float* gQ = qkv + headBase;
  const float* gK = gQ + (size_t)D * T_SEQ;
  const float* gV = gQ + (size_t)(2 * D) * T_SEQ;
  // reference quirk: jnp.tile(mask,(H,1)) -> row (b*H+h) % N == h % 4
  const float* gM = mask + (size_t)(bh & 3) * T_SEQ;

  // ---- per-thread staging geometry (K waves 0-3, V waves 4-7) ----
  const bool isK = tid < 256;
  const int t2 = tid & 255;
  const int ksb = 2 * (t2 & 31);        // K: s offset (2 rows)
  const int kcb = 8 * (t2 >> 5);        // K: 8 channels
  const int vc = t2 >> 2;               // V: channel
  const int vsb = 16 * (t2 & 3);        // V: 16 s
  const float* stagBase = isK ? (gK + (size_t)kcb * T_SEQ + ksb)
                              : (gV + (size_t)vc * T_SEQ + vsb);
  const int sstride = isK ? T_SEQ : 2;
  f32x2 g0, g1, g2, g3, g4, g5, g6, g7;  // in-flight K/V (never across a barrier)

  // ---- prologue: mask row (8KB) + stage Q transposed [q][c] ----
  *(f32x4*)&maskLds[tid * 4] = *(const f32x4*)&gM[tid * 4];
  {
    const int sb = (tid & 31) * 4;   // q within tile
    const int cb = (tid >> 5) * 4;   // channel
    const int q0 = qt * QBLK;
    const float qscale = 0.125f * LOG2E;  // 1/sqrt(64) * log2(e) folded in
    f32x4 r[4];
#pragma unroll
    for (int j = 0; j < 4; ++j)
      r[j] = *(const f32x4*)(gQ + (size_t)(cb + j) * T_SEQ + q0 + sb);
#pragma unroll
    for (int i = 0; i < 4; ++i) {
      s16x4 w;
#pragma unroll
      for (int j = 0; j < 4; ++j) w[j] = f2bf(r[j][i] * qscale);
      *(s16x4*)(Qc + swz(sb + i, 2 * cb)) = w;
    }
  }
  __syncthreads();   // Qc + maskLds visible

  const int wave = tid >> 6, lane = tid & 63;
  const int lg = lane >> 4, lid = lane & 15;

  // Q B-fragments for swapped QK^T: lane holds Q[q=wave*16+lid][k-slot 8lg+e]
  s16x8 aq[2];
#pragma unroll
  for (int ko = 0; ko < 2; ++ko)
    aq[ko] = *(const s16x8*)(Qc + swz(wave * 16 + lid, 16 * lg + 64 * ko));

  LOAD_G(stagBase);            // tile 0
  CONVERT_STORE(K0, V0, 0);    // K0/V0 disjoint from Qc: no barrier needed

  // per-lane softmax state (log2 domain) for q = qt*128 + wave*16 + lid
  float m0 = -1e30f, l0 = 0.0f;
  f32x4 accO[4];   // accO[ct][r] = O^T[c=16ct+4lg+r][q=lid]
#pragma unroll
  for (int ct = 0; ct < 4; ++ct) accO[ct] = (f32x4){0.f, 0.f, 0.f, 0.f};

  char* Pw = Pc + wave * 2048;     // [16 q=lid][64 s] bf16 swz
  char* Kcur = K0; char* Knx = K1;
  char* Vcur = V0; char* Vnx = V1;

  __syncthreads();   // K0/V0 visible; all aq ds_reads drained (Qc->Pc safe)

  for (int s0 = 0; s0 < T_SEQ; s0 += KVBLK) {
    // ---- issue next tile's loads (unconditional; last iter re-loads cur) ----
    const int snext = (s0 + KVBLK < T_SEQ) ? s0 + KVBLK : s0;
    LOAD_G(stagBase + snext);

    // ---- S^T = mfma(K, Q): C[s=16nt+4lg+r][q=lid], log2-scaled ----
    f32x4 accST[4];
#pragma unroll
    for (int nt = 0; nt < 4; ++nt) accST[nt] = (f32x4){0.f, 0.f, 0.f, 0.f};
    __builtin_amdgcn_s_setprio(1);
#pragma unroll
    for (int ko = 0; ko < 2; ++ko) {
#pragma unroll
      for (int nt = 0; nt < 4; ++nt) {
        s16x8 ak = *(const s16x8*)(Kcur + swz(nt * 16 + lid, 16 * lg + 64 * ko));
        accST[nt] = __builtin_amdgcn_mfma_f32_16x16x32_bf16(ak, aq[ko], accST[nt], 0, 0, 0);
      }
    }
    __builtin_amdgcn_s_setprio(0);

    // ---- per-lane online softmax (lane owns q=lid; s spread over lg) ----
    float mx[4];
#pragma unroll
    for (int nt = 0; nt < 4; ++nt)
      mx[nt] = fmaxf(fmaxf(accST[nt][0], accST[nt][1]),
                     fmaxf(accST[nt][2], accST[nt][3]));
    float tm = fmaxf(fmaxf(mx[0], mx[1]), fmaxf(mx[2], mx[3]));
    tm = fmaxf(tm, __shfl_xor(tm, 16));
    tm = fmaxf(tm, __shfl_xor(tm, 32));
    // T13 defer-rescale (log2 domain: 8*log2e)
    if (!__all(tm - m0 <= 11.5416f)) {
      const float nm = fmaxf(m0, tm);
      const float sc = fast_exp2(m0 - nm);
      m0 = nm;
      l0 *= sc;
#pragma unroll
      for (int ct = 0; ct < 4; ++ct) {
#pragma unroll
        for (int r = 0; r < 4; ++r) accO[ct][r] *= sc;
      }
    }
    float p[4][4], ps[4];
#pragma unroll
    for (int nt = 0; nt < 4; ++nt) {
#pragma unroll
      for (int r = 0; r < 4; ++r) p[nt][r] = fast_exp2(accST[nt][r] - m0);
      ps[nt] = (p[nt][0] + p[nt][1]) + (p[nt][2] + p[nt][3]);
    }
    float rs = (ps[0] + ps[1]) + (ps[2] + ps[3]);
    rs += __shfl_xor(rs, 16);
    rs += __shfl_xor(rs, 32);
    l0 += rs;   // denominator unmasked (ref: softmax before mask)

    // ---- P -> per-wave LDS, 4x 8B writes (conflict-free, pk-converts) ----
#pragma unroll
    for (int nt = 0; nt < 4; ++nt) {
      s16x4 w;
#pragma unroll
      for (int r = 0; r < 4; ++r) w[r] = f2bf(p[nt][r]);
      *(s16x4*)(Pw + swz(lid, 32 * nt + 8 * lg)) = w;
    }

    // ---- convert next tile into back buffers (vmcnt wait lands here,
    //      covered by QK^T + softmax above; no barrier crossed by g*) ----
    CONVERT_STORE(Knx, Vnx, snext);

    // ---- O^T += mfma(V, P): C[c=16ct+4lg+r][q=lid] ----
    // per-wave DS in-order: no barrier needed for Pw write->read
    __builtin_amdgcn_s_setprio(1);
#pragma unroll
    for (int ko = 0; ko < 2; ++ko) {
      s16x8 bp = *(const s16x8*)(Pw + swz(lid, 64 * ko + 16 * lg));
#pragma unroll
      for (int ct = 0; ct < 4; ++ct) {
        s16x8 av = *(const s16x8*)(Vcur + swz(ct * 16 + lid, 64 * ko + 16 * lg));
        accO[ct] = __builtin_amdgcn_mfma_f32_16x16x32_bf16(av, bp, accO[ct], 0, 0, 0);
      }
    }
    __builtin_amdgcn_s_setprio(0);

    // single barrier per iteration: nxt-buffer writes visible, cur reads done
    __syncthreads();
    char* t;
    t = Kcur; Kcur = Knx; Knx = t;
    t = Vcur; Vcur = Vnx; Vnx = t;
  }

  // ---- epilogue: direct stores, lanes lid=0..15 give 64B segments ----
  const float rcp = 1.0f / l0;
  const int qcol = qt * QBLK + wave * 16 + lid;
#pragma unroll
  for (int ct = 0; ct < 4; ++ct) {
#pragma unroll
    for (int r = 0; r < 4; ++r) {
      const int c = 16 * ct + 4 * lg + r;
      out[((size_t)(b * (H * D) + h * D + c)) * T_SEQ + qcol] = accO[ct][r] * rcp;
    }
  }
}

extern "C" void kernel_launch(void* const* d_in, const int* in_sizes, int n_in,
                              void* d_out, int out_size, void* d_ws, size_t ws_size,
                              hipStream_t stream) {
  const float* qkv = (const float*)d_in[0];
  const float* mask = (const float*)d_in[1];
  float* out = (float*)d_out;
  dim3 grid(T_SEQ / QBLK, 64);  // 16 q-tiles x 64 batch-heads
  attn_kernel<<<grid, NTHREADS, 0, stream>>>(qkv, mask, out);
}